// Round 7
// baseline (144.461 us; speedup 1.0000x reference)
//
#include <hip/hip_runtime.h>
#include <hip/hip_fp16.h>

// PairwiseScore: B=2, N=256, E=512, H=150 (padded to 160)
// out[b,i,j] = (m[b,i] + m[b,j] + MLP3(g_i, g_j)) / 3
//
// R10 = R9 (builder-free algebra, fp16, DMA'd static A) + 2D wave tiling.
//   D1[h][j] = W1c^T (g_i . g_j) + HJ[j] + HI[i] + b1   (HI/HJ precomputed)
// Waves: 8 = 2 h-halves x 4 j-groups. Each wave 5 ht x 4 jt:
//   - GEMM1 A-frag LDS reads HALVED (80/wave vs 160): was the top pipe
//     (12.8us of 47.6 across 2 rounds).
//   - h1 passes through the freed 80KB stage in MFMA B-FRAG-MAJOR layout:
//     epilogue writes and GEMM2 B-reads are bank-conflict-free, and the
//     ~600-op/wave shfl transform is DELETED.
//   - GEMM2 A-frags (W2^T, 50KB, L2/L1-hot, 4 waves share each row) read
//     direct from global; GEMM3 h-halves combined via 2KB scorebuf.
// acc stays 80 f32 (occupancy law: 2 waves/SIMD, 1 block/CU, 2 rounds --
// accepted; the attack is on per-block pipe floors, not occupancy).

typedef __attribute__((ext_vector_type(4))) float f32x4;
typedef __attribute__((ext_vector_type(4))) unsigned int u32x4;
typedef __attribute__((ext_vector_type(2))) unsigned int u32x2;
typedef __attribute__((ext_vector_type(8))) _Float16 f16x8;
typedef __attribute__((ext_vector_type(2))) _Float16 f16x2;

#define NN 256
#define NE 512
#define NH 150
#define HP 160      // padded H
#define NKT 16      // NE/32 k-tiles for GEMM1
#define NHT 10      // HP/16 h-tiles
#define NS 5        // HP/32 k-steps for GEMM2
#define WHT 5       // h-tiles per wave (h-half)
#define NJT 4       // j 16-col groups per wave

// ---------- helpers ----------
__device__ __forceinline__ unsigned pk_f16(float a, float b) {
  return __builtin_bit_cast(unsigned, __builtin_amdgcn_cvt_pkrtz(a, b));
}
__device__ __forceinline__ f16x8 prod8(u32x4 a, u32x4 b) {
  u32x4 p;
#pragma unroll
  for (int q = 0; q < 4; ++q) {
    f16x2 x = __builtin_bit_cast(f16x2, a[q]);
    f16x2 y = __builtin_bit_cast(f16x2, b[q]);
    p[q] = __builtin_bit_cast(unsigned, (f16x2)(x * y));
  }
  return __builtin_bit_cast(f16x8, p);
}
__device__ __forceinline__ void async_cp16(const unsigned* gsrc, unsigned* ldst) {
  __builtin_amdgcn_global_load_lds(
      (const __attribute__((address_space(1))) unsigned*)gsrc,
      (__attribute__((address_space(3))) unsigned*)ldst, 16, 0, 0);
}

// ---------- prep: grid 365 x 256 (proven R7 shape, fp16 pack) ----------
__global__ __launch_bounds__(256) void prep_pack(
    const float* __restrict__ g, const float* __restrict__ W1,
    const float* __restrict__ W2,
    unsigned short* __restrict__ g_f16, unsigned short* __restrict__ WaF,
    unsigned short* __restrict__ WbF, unsigned short* __restrict__ WcF,
    unsigned short* __restrict__ W2TF)
{
  __shared__ float tile[16][161];
  int bid = blockIdx.x, tid = threadIdx.x;
  if (bid < 256) {
    int t = bid * 256 + tid;
    f32x4 v = ((const f32x4*)g)[t];
    u32x2 o; o[0] = pk_f16(v[0], v[1]); o[1] = pk_f16(v[2], v[3]);
    ((u32x2*)g_f16)[t] = o;
  } else if (bid < 352) {
    int bb = bid - 256;
    int mat = bb >> 5;
    int kt = (bb & 31) >> 1;
    int half = bb & 1;
    const float* __restrict__ Wm =
        W1 + ((size_t)mat * NE + (size_t)kt * 32 + (size_t)half * 16) * NH;
    for (int idx = tid; idx < 16 * NH; idx += 256) {
      int e = idx / NH, h = idx - e * NH;
      tile[e][h] = Wm[idx];
    }
    for (int idx = tid; idx < 16 * 10; idx += 256)
      tile[idx / 10][NH + (idx % 10)] = 0.f;
    __syncthreads();
    unsigned short* dst = (mat == 0) ? WaF : (mat == 1) ? WbF : WcF;
#pragma unroll
    for (int r = 0; r < 2; ++r) {
      int rr = tid + r * 256;
      if (rr < 320) {
        int chh = rr >> 5;
        int l = half * 32 + (rr & 31);
        int el = ((l >> 4) & 1) * 8;
        int h = chh * 16 + (l & 15);
        u32x4 o;
#pragma unroll
        for (int q = 0; q < 4; ++q)
          o[q] = pk_f16(tile[el + 2 * q][h], tile[el + 2 * q + 1][h]);
        ((u32x4*)dst)[kt * 640 + chh * 64 + l] = o;
      }
    }
  } else {
    int row = (bid - 352) * 256 + tid;
    if (row < 3200) {
      int s = row / 640; int rem = row - s * 640;
      int l = rem & 63; int chh = rem >> 6;
      int k = s * 32 + (l >> 4) * 8;
      int hp = chh * 16 + (l & 15);
      u32x4 o;
#pragma unroll
      for (int q = 0; q < 4; ++q) {
        int k0 = k + 2 * q, k1 = k0 + 1;
        float v0 = (k0 < NH && hp < NH) ? W2[(size_t)k0 * NH + hp] : 0.f;
        float v1 = (k1 < NH && hp < NH) ? W2[(size_t)k1 * NH + hp] : 0.f;
        o[q] = pk_f16(v0, v1);
      }
      ((u32x4*)W2TF)[row] = o;
    }
  }
}

// ---------- prep_hij: HI[b,n,h]=sum_e g W1a ; HJ=sum_e g W1b ----------
__global__ __launch_bounds__(256) void prep_hij(
    const unsigned short* __restrict__ g_f16,
    const unsigned short* __restrict__ WaF,
    const unsigned short* __restrict__ WbF,
    float* __restrict__ HI, float* __restrict__ HJ)
{
  const int bid = blockIdx.x, tid = threadIdx.x;
  const int b = bid >> 4, nt = bid & 15;
  const int lane = tid & 63, wave = tid >> 6;
  const int c16 = lane & 15, quad = lane >> 4;
  const int mat = wave & 1, hh = wave >> 1;
  const u32x4* AF = (const u32x4*)(mat ? WbF : WaF);
  float* T = mat ? HJ : HI;
  const int n = nt * 16 + c16;
  const u32x4* gB = (const u32x4*)g_f16;
  const size_t gidx = (size_t)(b * NN + n) * 64 + quad;

  f32x4 acc[5] = {};
#pragma unroll
  for (int kt = 0; kt < NKT; ++kt) {
    f16x8 bf = __builtin_bit_cast(f16x8, gB[gidx + (size_t)kt * 4]);
#pragma unroll
    for (int t = 0; t < 5; ++t) {
      f16x8 af = __builtin_bit_cast(f16x8, AF[(kt * NHT + hh * 5 + t) * 64 + lane]);
      acc[t] = __builtin_amdgcn_mfma_f32_16x16x32_f16(af, bf, acc[t], 0, 0, 0);
    }
  }
#pragma unroll
  for (int t = 0; t < 5; ++t)
    *(f32x4*)(T + (size_t)(b * NN + n) * HP + (hh * 5 + t) * 16 + quad * 4) = acc[t];
}

// ---------- main kernel: 512 threads, one block per (b,i) ----------
__global__ __launch_bounds__(512) void pair_main(
    const float* __restrict__ mention, const float* __restrict__ b1,
    const float* __restrict__ b2, const float* __restrict__ W3,
    const float* __restrict__ b3,
    const unsigned short* __restrict__ g_f16,
    const unsigned short* __restrict__ W1cF,
    const unsigned short* __restrict__ W2TF,
    const float* __restrict__ HI, const float* __restrict__ HJ,
    float* __restrict__ out)
{
  __shared__ u32x4 stage[5120];             // 80 KB: 2x40KB W1cF dbuf, then h1
  __shared__ unsigned int gi_lds[NE / 2];   // g_i fp16 (1 KB)
  __shared__ alignas(16) float bias1[HP];   // b1 + HI[i]
  __shared__ alignas(16) float bias2[HP];
  __shared__ alignas(16) float w3s[HP];
  __shared__ float scorebuf[NN];            // h-half-1 GEMM3 partials (1 KB)

  const int tid = threadIdx.x;
  const int bi = blockIdx.x;
  const int b = bi >> 8, i = bi & 255;
  const int lane = tid & 63, wave = tid >> 6;   // 8 waves
  const int c16 = lane & 15, quad = lane >> 4;
  const int hh = wave >> 2, jg = wave & 3;      // h-half, j-group(64 cols)

  // ---- phase 0: per-block constants ----
  if (tid < 64) {
    const u32x4* grow = (const u32x4*)(g_f16 + (size_t)(b * NN + i) * NE);
    ((u32x4*)gi_lds)[tid] = grow[tid];
  } else if (tid >= 64 && tid < 64 + HP) {
    int h = tid - 64;
    bias1[h] = ((h < NH) ? b1[h] : 0.f) + HI[(size_t)(b * NN + i) * HP + h];
  } else if (tid >= 256 && tid < 256 + HP) {
    int h = tid - 256;
    bias2[h] = (h < NH) ? b2[h] : 0.f;
    w3s[h]   = (h < NH) ? W3[h] : 0.f;
  }

  // ---- DMA stager: mega m = 4 k-tiles of W1cF (40KB) into buf (m&1) ----
  auto stage_mega = [&](int m) {
    const unsigned* src = (const unsigned*)W1cF + (size_t)m * 2560 * 4;
    unsigned* dstb = (unsigned*)(stage + (m & 1) * 2560);
#pragma unroll
    for (int r = 0; r < 5; ++r) {
      int idx = tid + r * 512;               // 0..2559
      async_cp16(src + (size_t)idx * 4, dstb + idx * 4);
    }
  };

  f32x4 acc1[WHT][NJT] = {};
  const u32x4* gB = (const u32x4*)g_f16;
  const u32x4* giq = (const u32x4*)gi_lds;
  // wave's j cols: j = jg*64 + jt*16 + c16
  const size_t gidx0 = (size_t)(b * NN + jg * 64 + c16) * 64 + quad;

  // ---- GEMM1 mega: A (static W1c^T half) from LDS, B = g_i.g_j in regs ----
  auto gemm1_mega = [&](int m) {
    const u32x4* As = stage + (m & 1) * 2560;
#pragma unroll
    for (int ktl = 0; ktl < 4; ++ktl) {
      int ktg = m * 4 + ktl;
      u32x4 gi4 = giq[ktg * 4 + quad];                 // broadcast slice
      f16x8 bf[NJT];
#pragma unroll
      for (int jt = 0; jt < NJT; ++jt) {
        u32x4 gj = gB[gidx0 + (size_t)(jt * 16 * 64) + (size_t)ktg * 4];
        bf[jt] = prod8(gj, gi4);
      }
#pragma unroll
      for (int ht = 0; ht < WHT; ++ht) {
        f16x8 af = __builtin_bit_cast(f16x8,
            As[ktl * 640 + (hh * WHT + ht) * 64 + lane]);
#pragma unroll
        for (int jt = 0; jt < NJT; ++jt)
          acc1[ht][jt] = __builtin_amdgcn_mfma_f32_16x16x32_f16(
              af, bf[jt], acc1[ht][jt], 0, 0, 0);
      }
    }
  };

  stage_mega(0);
  stage_mega(1);
  __syncthreads();   // B0: megas 0,1 + phase-0 LDS ready
  gemm1_mega(0);
  __syncthreads();   // B1: buf0 reads done
  stage_mega(2);     // DMA overlaps compute of mega 1
  gemm1_mega(1);
  __syncthreads();   // B2: mega-2 ready, buf1 reads done
  stage_mega(3);     // DMA overlaps compute of mega 2
  gemm1_mega(2);
  __syncthreads();   // B3: mega-3 ready
  gemm1_mega(3);
  __syncthreads();   // B4: all stage reads done -> stage becomes h1

  // ---- epilogue 1: h1 = relu(D1 + bias1 + HJ[j]) -> fp16 into stage,
  //      B-FRAG-MAJOR: frag (s, jtg) at [(s*16+jtg)*64 + kq*16 + c16]*16B,
  //      lane kq*16+c16 holds k = s*32 + kq*8 .. +8 (two 8B halves). ----
  {
    char* h1 = (char*)stage;
#pragma unroll
    for (int ht = 0; ht < WHT; ++ht) {
      int hbase = hh * 80 + ht * 16 + quad * 4;   // 4 consecutive h
      int s = hbase >> 5, kq = (hbase >> 3) & 3, off = hbase & 7;  // off=0|4
      f32x4 bv = *(const f32x4*)(bias1 + hbase);
#pragma unroll
      for (int jt = 0; jt < NJT; ++jt) {
        int j = jg * 64 + jt * 16 + c16;
        int jtg = jg * 4 + jt;
        f32x4 hj = *(const f32x4*)(HJ + (size_t)(b * NN + j) * HP + hbase);
        f32x4 v = acc1[ht][jt];
        float r0 = fmaxf(v[0] + bv[0] + hj[0], 0.f);
        float r1 = fmaxf(v[1] + bv[1] + hj[1], 0.f);
        float r2 = fmaxf(v[2] + bv[2] + hj[2], 0.f);
        float r3 = fmaxf(v[3] + bv[3] + hj[3], 0.f);
        u32x2 o; o[0] = pk_f16(r0, r1); o[1] = pk_f16(r2, r3);
        *(u32x2*)(h1 + ((s * 16 + jtg) * 64 + kq * 16 + c16) * 16 + off * 2) = o;
      }
    }
  }
  __syncthreads();   // B5: h1 complete

  // ---- phase 2: D2 = W2^T h1 ; B-frags from LDS h1 (frag-major, no
  //      transform), A2 frags direct from L2/L1 (50KB hot, 4 waves share) ----
  f32x4 acc2[WHT][NJT] = {};
  {
    const u32x4* A2g = (const u32x4*)W2TF;
#pragma unroll
    for (int s = 0; s < NS; ++s) {
      f16x8 b2f[NJT];
#pragma unroll
      for (int jt = 0; jt < NJT; ++jt)
        b2f[jt] = __builtin_bit_cast(f16x8, stage[(s * 16 + jg * 4 + jt) * 64 + lane]);
#pragma unroll
      for (int ht = 0; ht < WHT; ++ht) {
        f16x8 af = __builtin_bit_cast(f16x8,
            A2g[(s * NHT + hh * WHT + ht) * 64 + lane]);
#pragma unroll
        for (int jt = 0; jt < NJT; ++jt)
          acc2[ht][jt] = __builtin_amdgcn_mfma_f32_16x16x32_f16(
              af, b2f[jt], acc2[ht][jt], 0, 0, 0);
      }
    }
  }

  // ---- epilogue 2 + GEMM3: partial over this wave's 5 ht' ----
  float part[NJT] = {};
#pragma unroll
  for (int ht = 0; ht < WHT; ++ht) {
    int hbase = hh * 80 + ht * 16 + quad * 4;
    f32x4 bv = *(const f32x4*)(bias2 + hbase);
    f32x4 wv = *(const f32x4*)(w3s + hbase);
#pragma unroll
    for (int jt = 0; jt < NJT; ++jt) {
      f32x4 v = acc2[ht][jt];
#pragma unroll
      for (int r = 0; r < 4; ++r)
        part[jt] += fmaxf(v[r] + bv[r], 0.f) * wv[r];
    }
  }
#pragma unroll
  for (int jt = 0; jt < NJT; ++jt) {
    part[jt] += __shfl_xor(part[jt], 16);
    part[jt] += __shfl_xor(part[jt], 32);
  }
  if (hh == 1 && quad == 0) {
#pragma unroll
    for (int jt = 0; jt < NJT; ++jt)
      scorebuf[jg * 64 + jt * 16 + c16] = part[jt];
  }
  __syncthreads();   // B6: half-1 partials visible

  if (hh == 0 && quad == 0) {
    const float mi = mention[b * NN + i];
    const float b3v = b3[0];
#pragma unroll
    for (int jt = 0; jt < NJT; ++jt) {
      int j = jg * 64 + jt * 16 + c16;
      float sc = part[jt] + scorebuf[j];
      float mj = mention[b * NN + j];
      out[((size_t)(b * NN + i)) * NN + j] = (mi + mj + sc + b3v) * (1.f / 3.f);
    }
  }
}

// ---------- launch ----------
extern "C" void kernel_launch(void* const* d_in, const int* in_sizes, int n_in,
                              void* d_out, int out_size, void* d_ws, size_t ws_size,
                              hipStream_t stream) {
  const float* g  = (const float*)d_in[0];
  const float* m  = (const float*)d_in[1];
  const float* W1 = (const float*)d_in[2];
  const float* b1 = (const float*)d_in[3];
  const float* W2 = (const float*)d_in[4];
  const float* b2 = (const float*)d_in[5];
  const float* W3 = (const float*)d_in[6];
  const float* b3 = (const float*)d_in[7];
  float* out = (float*)d_out;

  char* ws = (char*)d_ws;
  unsigned short* g_f16 = (unsigned short*)(ws);               // 524288 B
  unsigned short* WaF   = (unsigned short*)(ws + 524288);      // 163840 B
  unsigned short* WbF   = (unsigned short*)(ws + 688128);      // 163840 B
  unsigned short* WcF   = (unsigned short*)(ws + 851968);      // 163840 B
  unsigned short* W2TF  = (unsigned short*)(ws + 1015808);     //  51200 B
  float*          HI    = (float*)(ws + 1067008);              // 327680 B
  float*          HJ    = (float*)(ws + 1394688);              // 327680 B -> 1.72MB

  prep_pack<<<365, 256, 0, stream>>>(g, W1, W2, g_f16, WaF, WbF, WcF, W2TF);
  prep_hij<<<32, 256, 0, stream>>>(g_f16, WaF, WbF, HI, HJ);
  pair_main<<<512, 512, 0, stream>>>(m, b1, b2, W3, b3, g_f16, WcF, W2TF,
                                     HI, HJ, out);
}

// Round 8
// 136.038 us; speedup vs baseline: 1.0619x; 1.0619x over previous
//
#include <hip/hip_runtime.h>
#include <hip/hip_fp16.h>

// PairwiseScore: B=2, N=256, E=512, H=150 (padded to 160)
// out[b,i,j] = (m[b,i] + m[b,j] + MLP3(g_i, g_j)) / 3
//
// R11: TWO INDEPENDENT BLOCKS PER CU (the untried cell).
// Evidence: R8 proved extra waves of the SAME block don't help (lockstep
// barriers); R1/R5 proved wider acc spills; R7 proved LDS-only shrink fails
// (regs cap at 2 waves/SIMD); R10 proved moving operands to global at low
// occupancy exposes latency. Fix: halve the output tile.
//   1024 blocks, tile 160x128: 8 waves = 2 h-halves x 4 j-groups,
//   wave = 5ht x 2jt -> acc1 40 f32 -> ~100 unified regs -> 4 waves/SIMD.
//   LDS ~44KB (2x20KB W1cF dbuf, reused as 40KB h1) -> 2 blocks/CU.
//   One block's barrier stalls overlap the other block's MFMA/DMA.
// Kept from R9/R10 (proven): builder-free algebra (g_i.g_j on B-side via
// v_pk_mul_f16), DMA'd static A, HI/HJ tables, B-frag-major h1 LDS layout
// (no shfl transform), GEMM2 A from L2 (now latency-hidden), scorebuf tail.

typedef __attribute__((ext_vector_type(4))) float f32x4;
typedef __attribute__((ext_vector_type(4))) unsigned int u32x4;
typedef __attribute__((ext_vector_type(2))) unsigned int u32x2;
typedef __attribute__((ext_vector_type(8))) _Float16 f16x8;
typedef __attribute__((ext_vector_type(2))) _Float16 f16x2;

#define NN 256
#define NE 512
#define NH 150
#define HP 160      // padded H
#define NKT 16      // NE/32 k-tiles for GEMM1
#define NHT 10      // HP/16 h-tiles
#define NS 5        // HP/32 k-steps for GEMM2
#define WHT 5       // h-tiles per wave (h-half)
#define NJT 2       // j 16-col groups per wave
#define MKT 2       // k-tiles per mega (20KB)
#define NMEGA 8

// ---------- helpers ----------
__device__ __forceinline__ unsigned pk_f16(float a, float b) {
  return __builtin_bit_cast(unsigned, __builtin_amdgcn_cvt_pkrtz(a, b));
}
__device__ __forceinline__ f16x8 prod8(u32x4 a, u32x4 b) {
  u32x4 p;
#pragma unroll
  for (int q = 0; q < 4; ++q) {
    f16x2 x = __builtin_bit_cast(f16x2, a[q]);
    f16x2 y = __builtin_bit_cast(f16x2, b[q]);
    p[q] = __builtin_bit_cast(unsigned, (f16x2)(x * y));
  }
  return __builtin_bit_cast(f16x8, p);
}
__device__ __forceinline__ void async_cp16(const unsigned* gsrc, unsigned* ldst) {
  __builtin_amdgcn_global_load_lds(
      (const __attribute__((address_space(1))) unsigned*)gsrc,
      (__attribute__((address_space(3))) unsigned*)ldst, 16, 0, 0);
}

// ---------- prep: grid 365 x 256 (proven shape, fp16 pack) ----------
__global__ __launch_bounds__(256) void prep_pack(
    const float* __restrict__ g, const float* __restrict__ W1,
    const float* __restrict__ W2,
    unsigned short* __restrict__ g_f16, unsigned short* __restrict__ WaF,
    unsigned short* __restrict__ WbF, unsigned short* __restrict__ WcF,
    unsigned short* __restrict__ W2TF)
{
  __shared__ float tile[16][161];
  int bid = blockIdx.x, tid = threadIdx.x;
  if (bid < 256) {
    int t = bid * 256 + tid;
    f32x4 v = ((const f32x4*)g)[t];
    u32x2 o; o[0] = pk_f16(v[0], v[1]); o[1] = pk_f16(v[2], v[3]);
    ((u32x2*)g_f16)[t] = o;
  } else if (bid < 352) {
    int bb = bid - 256;
    int mat = bb >> 5;
    int kt = (bb & 31) >> 1;
    int half = bb & 1;
    const float* __restrict__ Wm =
        W1 + ((size_t)mat * NE + (size_t)kt * 32 + (size_t)half * 16) * NH;
    for (int idx = tid; idx < 16 * NH; idx += 256) {
      int e = idx / NH, h = idx - e * NH;
      tile[e][h] = Wm[idx];
    }
    for (int idx = tid; idx < 16 * 10; idx += 256)
      tile[idx / 10][NH + (idx % 10)] = 0.f;
    __syncthreads();
    unsigned short* dst = (mat == 0) ? WaF : (mat == 1) ? WbF : WcF;
#pragma unroll
    for (int r = 0; r < 2; ++r) {
      int rr = tid + r * 256;
      if (rr < 320) {
        int chh = rr >> 5;
        int l = half * 32 + (rr & 31);
        int el = ((l >> 4) & 1) * 8;
        int h = chh * 16 + (l & 15);
        u32x4 o;
#pragma unroll
        for (int q = 0; q < 4; ++q)
          o[q] = pk_f16(tile[el + 2 * q][h], tile[el + 2 * q + 1][h]);
        ((u32x4*)dst)[kt * 640 + chh * 64 + l] = o;
      }
    }
  } else {
    int row = (bid - 352) * 256 + tid;
    if (row < 3200) {
      int s = row / 640; int rem = row - s * 640;
      int l = rem & 63; int chh = rem >> 6;
      int k = s * 32 + (l >> 4) * 8;
      int hp = chh * 16 + (l & 15);
      u32x4 o;
#pragma unroll
      for (int q = 0; q < 4; ++q) {
        int k0 = k + 2 * q, k1 = k0 + 1;
        float v0 = (k0 < NH && hp < NH) ? W2[(size_t)k0 * NH + hp] : 0.f;
        float v1 = (k1 < NH && hp < NH) ? W2[(size_t)k1 * NH + hp] : 0.f;
        o[q] = pk_f16(v0, v1);
      }
      ((u32x4*)W2TF)[row] = o;
    }
  }
}

// ---------- prep_hij: HI[b,n,h]=sum_e g W1a ; HJ=sum_e g W1b ----------
__global__ __launch_bounds__(256) void prep_hij(
    const unsigned short* __restrict__ g_f16,
    const unsigned short* __restrict__ WaF,
    const unsigned short* __restrict__ WbF,
    float* __restrict__ HI, float* __restrict__ HJ)
{
  const int bid = blockIdx.x, tid = threadIdx.x;
  const int b = bid >> 4, nt = bid & 15;
  const int lane = tid & 63, wave = tid >> 6;
  const int c16 = lane & 15, quad = lane >> 4;
  const int mat = wave & 1, hh = wave >> 1;
  const u32x4* AF = (const u32x4*)(mat ? WbF : WaF);
  float* T = mat ? HJ : HI;
  const int n = nt * 16 + c16;
  const u32x4* gB = (const u32x4*)g_f16;
  const size_t gidx = (size_t)(b * NN + n) * 64 + quad;

  f32x4 acc[5] = {};
#pragma unroll
  for (int kt = 0; kt < NKT; ++kt) {
    f16x8 bf = __builtin_bit_cast(f16x8, gB[gidx + (size_t)kt * 4]);
#pragma unroll
    for (int t = 0; t < 5; ++t) {
      f16x8 af = __builtin_bit_cast(f16x8, AF[(kt * NHT + hh * 5 + t) * 64 + lane]);
      acc[t] = __builtin_amdgcn_mfma_f32_16x16x32_f16(af, bf, acc[t], 0, 0, 0);
    }
  }
#pragma unroll
  for (int t = 0; t < 5; ++t)
    *(f32x4*)(T + (size_t)(b * NN + n) * HP + (hh * 5 + t) * 16 + quad * 4) = acc[t];
}

// ---------- main kernel: 512 threads, one block per (b,i,jhalf) ----------
__global__ __launch_bounds__(512) void pair_main(
    const float* __restrict__ mention, const float* __restrict__ b1,
    const float* __restrict__ b2, const float* __restrict__ W3,
    const float* __restrict__ b3,
    const unsigned short* __restrict__ g_f16,
    const unsigned short* __restrict__ W1cF,
    const unsigned short* __restrict__ W2TF,
    const float* __restrict__ HI, const float* __restrict__ HJ,
    float* __restrict__ out)
{
  __shared__ u32x4 stage[2560];             // 40 KB: 2x20KB W1cF dbuf -> h1
  __shared__ unsigned int gi_lds[NE / 2];   // g_i fp16 (1 KB)
  __shared__ alignas(16) float bias1[HP];   // b1 + HI[i]
  __shared__ alignas(16) float bias2[HP];
  __shared__ alignas(16) float w3s[HP];
  __shared__ float scorebuf[128];           // h-half-1 GEMM3 partials

  const int tid = threadIdx.x;
  const int bi = blockIdx.x;                // 1024 blocks
  const int jhalf = bi & 1, i = (bi >> 1) & 255, b = bi >> 9;
  const int lane = tid & 63, wave = tid >> 6;   // 8 waves
  const int c16 = lane & 15, quad = lane >> 4;
  const int hh = wave >> 2, jg = wave & 3;      // h-half, j-group(32 cols)

  // ---- phase 0: per-block constants ----
  if (tid < 64) {
    const u32x4* grow = (const u32x4*)(g_f16 + (size_t)(b * NN + i) * NE);
    ((u32x4*)gi_lds)[tid] = grow[tid];
  } else if (tid >= 64 && tid < 64 + HP) {
    int h = tid - 64;
    bias1[h] = ((h < NH) ? b1[h] : 0.f) + HI[(size_t)(b * NN + i) * HP + h];
  } else if (tid >= 256 && tid < 256 + HP) {
    int h = tid - 256;
    bias2[h] = (h < NH) ? b2[h] : 0.f;
    w3s[h]   = (h < NH) ? W3[h] : 0.f;
  }

  // ---- DMA stager: mega m = 2 k-tiles of W1cF (20KB) into buf (m&1) ----
  auto stage_mega = [&](int m) {
    const unsigned* src = (const unsigned*)W1cF + (size_t)m * 1280 * 4;
    unsigned* dstb = (unsigned*)(stage + (m & 1) * 1280);
    {
      async_cp16(src + (size_t)tid * 4, dstb + tid * 4);
      async_cp16(src + (size_t)(tid + 512) * 4, dstb + (tid + 512) * 4);
      if (tid < 256)
        async_cp16(src + (size_t)(tid + 1024) * 4, dstb + (tid + 1024) * 4);
    }
  };

  f32x4 acc1[WHT][NJT] = {};
  const u32x4* gB = (const u32x4*)g_f16;
  const u32x4* giq = (const u32x4*)gi_lds;
  // wave's j cols: j = jhalf*128 + jg*32 + jt*16 + c16
  const int jbase = jhalf * 128 + jg * 32;
  const size_t gidx0 = (size_t)(b * NN + jbase + c16) * 64 + quad;

  // ---- GEMM1 mega: A (static W1c^T h-half) from LDS, B = g_i.g_j in regs ----
  auto gemm1_mega = [&](int m) {
    const u32x4* As = stage + (m & 1) * 1280;
#pragma unroll
    for (int ktl = 0; ktl < MKT; ++ktl) {
      int ktg = m * MKT + ktl;
      u32x4 gi4 = giq[ktg * 4 + quad];                 // broadcast slice
      f16x8 bf[NJT];
#pragma unroll
      for (int jt = 0; jt < NJT; ++jt) {
        u32x4 gj = gB[gidx0 + (size_t)(jt * 16 * 64) + (size_t)ktg * 4];
        bf[jt] = prod8(gj, gi4);
      }
#pragma unroll
      for (int ht = 0; ht < WHT; ++ht) {
        f16x8 af = __builtin_bit_cast(f16x8,
            As[ktl * 640 + (hh * WHT + ht) * 64 + lane]);
#pragma unroll
        for (int jt = 0; jt < NJT; ++jt)
          acc1[ht][jt] = __builtin_amdgcn_mfma_f32_16x16x32_f16(
              af, bf[jt], acc1[ht][jt], 0, 0, 0);
      }
    }
  };

  stage_mega(0);
  stage_mega(1);
  __syncthreads();                 // B0: bufs 0,1 + phase-0 LDS ready
  gemm1_mega(0); __syncthreads(); stage_mega(2);
  gemm1_mega(1); __syncthreads(); stage_mega(3);
  gemm1_mega(2); __syncthreads(); stage_mega(4);
  gemm1_mega(3); __syncthreads(); stage_mega(5);
  gemm1_mega(4); __syncthreads(); stage_mega(6);
  gemm1_mega(5); __syncthreads(); stage_mega(7);
  gemm1_mega(6); __syncthreads();
  gemm1_mega(7); __syncthreads();  // all stage reads done -> stage becomes h1

  // ---- epilogue 1: h1 = relu(D1 + bias1 + HJ[j]) -> fp16 into stage,
  //      B-FRAG-MAJOR: frag (s, jtg) at [(s*8+jtg)*64 + kq*16 + c16]*16B ----
  {
    char* h1 = (char*)stage;
#pragma unroll
    for (int ht = 0; ht < WHT; ++ht) {
      int hbase = hh * 80 + ht * 16 + quad * 4;   // 4 consecutive h
      int s = hbase >> 5, kq = (hbase >> 3) & 3, off = hbase & 7;  // off=0|4
      f32x4 bv = *(const f32x4*)(bias1 + hbase);
#pragma unroll
      for (int jt = 0; jt < NJT; ++jt) {
        int j = jbase + jt * 16 + c16;
        int jtg = jg * 2 + jt;
        f32x4 hj = *(const f32x4*)(HJ + (size_t)(b * NN + j) * HP + hbase);
        f32x4 v = acc1[ht][jt];
        float r0 = fmaxf(v[0] + bv[0] + hj[0], 0.f);
        float r1 = fmaxf(v[1] + bv[1] + hj[1], 0.f);
        float r2 = fmaxf(v[2] + bv[2] + hj[2], 0.f);
        float r3 = fmaxf(v[3] + bv[3] + hj[3], 0.f);
        u32x2 o; o[0] = pk_f16(r0, r1); o[1] = pk_f16(r2, r3);
        *(u32x2*)(h1 + ((s * 8 + jtg) * 64 + kq * 16 + c16) * 16 + off * 2) = o;
      }
    }
  }
  __syncthreads();   // h1 complete

  // ---- phase 2: D2 = W2^T h1 ; B-frags from LDS h1 (frag-major), A2 from
  //      L2 (50KB shared by all 1024 blocks; latency hidden by 2 blocks/CU) ----
  f32x4 acc2[WHT][NJT] = {};
  {
    const u32x4* A2g = (const u32x4*)W2TF;
#pragma unroll
    for (int s = 0; s < NS; ++s) {
      f16x8 b2f[NJT];
#pragma unroll
      for (int jt = 0; jt < NJT; ++jt)
        b2f[jt] = __builtin_bit_cast(f16x8, stage[(s * 8 + jg * 2 + jt) * 64 + lane]);
#pragma unroll
      for (int ht = 0; ht < WHT; ++ht) {
        f16x8 af = __builtin_bit_cast(f16x8,
            A2g[(s * NHT + hh * WHT + ht) * 64 + lane]);
#pragma unroll
        for (int jt = 0; jt < NJT; ++jt)
          acc2[ht][jt] = __builtin_amdgcn_mfma_f32_16x16x32_f16(
              af, b2f[jt], acc2[ht][jt], 0, 0, 0);
      }
    }
  }

  // ---- epilogue 2 + GEMM3: partial over this wave's 5 ht' ----
  float part[NJT] = {};
#pragma unroll
  for (int ht = 0; ht < WHT; ++ht) {
    int hbase = hh * 80 + ht * 16 + quad * 4;
    f32x4 bv = *(const f32x4*)(bias2 + hbase);
    f32x4 wv = *(const f32x4*)(w3s + hbase);
#pragma unroll
    for (int jt = 0; jt < NJT; ++jt) {
      f32x4 v = acc2[ht][jt];
#pragma unroll
      for (int r = 0; r < 4; ++r)
        part[jt] += fmaxf(v[r] + bv[r], 0.f) * wv[r];
    }
  }
#pragma unroll
  for (int jt = 0; jt < NJT; ++jt) {
    part[jt] += __shfl_xor(part[jt], 16);
    part[jt] += __shfl_xor(part[jt], 32);
  }
  if (hh == 1 && quad == 0) {
#pragma unroll
    for (int jt = 0; jt < NJT; ++jt)
      scorebuf[jg * 32 + jt * 16 + c16] = part[jt];
  }
  __syncthreads();   // half-1 partials visible

  if (hh == 0 && quad == 0) {
    const float mi = mention[b * NN + i];
    const float b3v = b3[0];
#pragma unroll
    for (int jt = 0; jt < NJT; ++jt) {
      int j = jbase + jt * 16 + c16;
      float sc = part[jt] + scorebuf[jg * 32 + jt * 16 + c16];
      float mj = mention[b * NN + j];
      out[((size_t)(b * NN + i)) * NN + j] = (mi + mj + sc + b3v) * (1.f / 3.f);
    }
  }
}

// ---------- launch ----------
extern "C" void kernel_launch(void* const* d_in, const int* in_sizes, int n_in,
                              void* d_out, int out_size, void* d_ws, size_t ws_size,
                              hipStream_t stream) {
  const float* g  = (const float*)d_in[0];
  const float* m  = (const float*)d_in[1];
  const float* W1 = (const float*)d_in[2];
  const float* b1 = (const float*)d_in[3];
  const float* W2 = (const float*)d_in[4];
  const float* b2 = (const float*)d_in[5];
  const float* W3 = (const float*)d_in[6];
  const float* b3 = (const float*)d_in[7];
  float* out = (float*)d_out;

  char* ws = (char*)d_ws;
  unsigned short* g_f16 = (unsigned short*)(ws);               // 524288 B
  unsigned short* WaF   = (unsigned short*)(ws + 524288);      // 163840 B
  unsigned short* WbF   = (unsigned short*)(ws + 688128);      // 163840 B
  unsigned short* WcF   = (unsigned short*)(ws + 851968);      // 163840 B
  unsigned short* W2TF  = (unsigned short*)(ws + 1015808);     //  51200 B
  float*          HI    = (float*)(ws + 1067008);              // 327680 B
  float*          HJ    = (float*)(ws + 1394688);              // 327680 B -> 1.72MB

  prep_pack<<<365, 256, 0, stream>>>(g, W1, W2, g_f16, WaF, WbF, WcF, W2TF);
  prep_hij<<<32, 256, 0, stream>>>(g_f16, WaF, WbF, HI, HJ);
  pair_main<<<1024, 512, 0, stream>>>(m, b1, b2, W3, b3, g_f16, WcF, W2TF,
                                      HI, HJ, out);
}